// Round 1
// baseline (164.251 us; speedup 1.0000x reference)
//
#include <hip/hip_runtime.h>
#include <hip/hip_bf16.h>

typedef unsigned short u16;
typedef unsigned int u32;
typedef __attribute__((ext_vector_type(8))) short short8;
typedef __attribute__((ext_vector_type(4))) float f32x4;

#define L_SEQ 4096
#define NCH 64
#define NBATCH 4

__device__ inline u16 f2bf(float f) {
    union { float f; u32 u; } v; v.f = f;
    u32 r = v.u + 0x7fffu + ((v.u >> 16) & 1u);   // round-to-nearest-even
    return (u16)(r >> 16);
}

// ---------------- Kernel 1: QKV projection (3x 64x64 channel GEMM) ----------------
// Qt[n][i][c] (bf16), Kt[n][j][c] (bf16), V[n][c][j] (bf16)
__global__ __launch_bounds__(256) void qkv_kernel(
    const float* __restrict__ x,
    const float* __restrict__ wb, const float* __restrict__ bb,
    const float* __restrict__ wc, const float* __restrict__ bc,
    const float* __restrict__ wd, const float* __restrict__ bd,
    u16* __restrict__ Qt, u16* __restrict__ Kt, u16* __restrict__ V)
{
    __shared__ float xs[64][64];       // x tile: [c][px]
    __shared__ float wl[3][64][65];    // padded weights: [mat][o][c]

    const int nb  = blockIdx.y;
    const int i0  = blockIdx.x * 64;
    const int tid = threadIdx.x;

    const float* xbase = x + (size_t)nb * NCH * L_SEQ + i0;
    #pragma unroll
    for (int rep = 0; rep < 16; ++rep) {
        int idx = rep * 256 + tid;
        int c = idx >> 6, px = idx & 63;
        xs[c][px] = xbase[(size_t)c * L_SEQ + px];
    }
    const float* wsrc[3] = { wb, wc, wd };
    for (int m = 0; m < 3; ++m) {
        #pragma unroll
        for (int rep = 0; rep < 16; ++rep) {
            int idx = rep * 256 + tid;
            wl[m][idx >> 6][idx & 63] = wsrc[m][idx];
        }
    }
    __syncthreads();

    const int co  = tid & 63;     // output channel
    const int pg  = tid >> 6;     // pixel group 0..3
    const int px0 = pg * 16;

    float accB[16], accC[16], accD[16];
    const float biasB = bb[co], biasC = bc[co], biasD = bd[co];
    #pragma unroll
    for (int p = 0; p < 16; ++p) { accB[p] = biasB; accC[p] = biasC; accD[p] = biasD; }

    for (int c = 0; c < 64; ++c) {
        const float wbv = wl[0][co][c];
        const float wcv = wl[1][co][c];
        const float wdv = wl[2][co][c];
        #pragma unroll
        for (int p = 0; p < 16; ++p) {
            const float xv = xs[c][px0 + p];
            accB[p] += wbv * xv;
            accC[p] += wcv * xv;
            accD[p] += wdv * xv;
        }
    }

    #pragma unroll
    for (int p = 0; p < 16; ++p) {
        const int i = i0 + px0 + p;
        Kt[((size_t)(nb * L_SEQ + i)) * NCH + co] = f2bf(accB[p]);  // keys    = xb
        Qt[((size_t)(nb * L_SEQ + i)) * NCH + co] = f2bf(accC[p]);  // queries = xc
        V [((size_t)(nb * NCH + co)) * L_SEQ + i] = f2bf(accD[p]);  // values  = xd
    }
}

// ---------------- Kernel 2: flash attention + epilogue ----------------
// One wave (64 threads) owns 16 q-rows; iterates KV in tiles of 64.
__global__ __launch_bounds__(64) void attn_kernel(
    const u16* __restrict__ Qt, const u16* __restrict__ Kt,
    const u16* __restrict__ V,  const float* __restrict__ x,
    const float* __restrict__ alphap, float* __restrict__ out)
{
    __shared__ u16 pbuf[16][72];   // P transpose buffer, padded stride (144B)

    const int nb   = blockIdx.y;
    const int i0   = blockIdx.x * 16;
    const int lane = threadIdx.x;
    const int lo   = lane & 15;
    const int hi   = lane >> 4;

    // Q fragments: A[row=lo][k=c], c contiguous per lane
    short8 qf0, qf1;
    {
        const u16* qrow = Qt + ((size_t)(nb * L_SEQ + i0 + lo)) * NCH + hi * 8;
        qf0 = *(const short8*)(qrow);
        qf1 = *(const short8*)(qrow + 32);
    }

    const f32x4 zero = { 0.f, 0.f, 0.f, 0.f };
    f32x4 acc_o[4];
    #pragma unroll
    for (int ct = 0; ct < 4; ++ct) acc_o[ct] = zero;
    float m_[4], l_[4];
    #pragma unroll
    for (int r = 0; r < 4; ++r) { m_[r] = -3.0e38f; l_[r] = 0.f; }

    const u16* KtB = Kt + (size_t)nb * L_SEQ * NCH;
    const u16* VB  = V  + (size_t)nb * NCH * L_SEQ;

    #pragma unroll 1
    for (int j0 = 0; j0 < L_SEQ; j0 += 64) {
        // ---- S = Q K^T (16 x 64) ----
        f32x4 s[4];
        #pragma unroll
        for (int jt = 0; jt < 4; ++jt) {
            const u16* krow = KtB + ((size_t)(j0 + jt * 16 + lo)) * NCH + hi * 8;
            short8 k0 = *(const short8*)(krow);
            short8 k1 = *(const short8*)(krow + 32);
            f32x4 a = zero;
            a = __builtin_amdgcn_mfma_f32_16x16x32_bf16(qf0, k0, a, 0, 0, 0);
            a = __builtin_amdgcn_mfma_f32_16x16x32_bf16(qf1, k1, a, 0, 0, 0);
            s[jt] = a;
        }

        // ---- online softmax; D-layout: row q = hi*4 + r, col j = jt*16 + lo ----
        float scl[4];
        float pv[4][4];  // [jt][r]
        #pragma unroll
        for (int r = 0; r < 4; ++r) {
            float rm = fmaxf(fmaxf(s[0][r], s[1][r]), fmaxf(s[2][r], s[3][r]));
            #pragma unroll
            for (int msk = 1; msk < 16; msk <<= 1)
                rm = fmaxf(rm, __shfl_xor(rm, msk, 64));
            const float mn = fmaxf(m_[r], rm);
            scl[r] = __expf(m_[r] - mn);
            float rs = 0.f;
            #pragma unroll
            for (int jt = 0; jt < 4; ++jt) {
                const float p = __expf(s[jt][r] - mn);
                pv[jt][r] = p;
                rs += p;
            }
            #pragma unroll
            for (int msk = 1; msk < 16; msk <<= 1)
                rs += __shfl_xor(rs, msk, 64);
            l_[r] = l_[r] * scl[r] + rs;
            m_[r] = mn;
        }

        // ---- P -> LDS (transpose to A-fragment layout) ----
        #pragma unroll
        for (int jt = 0; jt < 4; ++jt)
            #pragma unroll
            for (int r = 0; r < 4; ++r)
                pbuf[hi * 4 + r][jt * 16 + lo] = f2bf(pv[jt][r]);
        __syncthreads();

        short8 pf0 = *(const short8*)&pbuf[lo][hi * 8];
        short8 pf1 = *(const short8*)&pbuf[lo][32 + hi * 8];

        // ---- rescale O ----
        #pragma unroll
        for (int ct = 0; ct < 4; ++ct)
            #pragma unroll
            for (int r = 0; r < 4; ++r)
                acc_o[ct][r] *= scl[r];

        // ---- O += P V^T ;  B[k=j][col=c] from V[c][j] (j contiguous) ----
        #pragma unroll
        for (int ct = 0; ct < 4; ++ct) {
            const u16* vrow = VB + ((size_t)(ct * 16 + lo)) * L_SEQ + j0 + hi * 8;
            short8 v0 = *(const short8*)(vrow);
            short8 v1 = *(const short8*)(vrow + 32);
            acc_o[ct] = __builtin_amdgcn_mfma_f32_16x16x32_bf16(pf0, v0, acc_o[ct], 0, 0, 0);
            acc_o[ct] = __builtin_amdgcn_mfma_f32_16x16x32_bf16(pf1, v1, acc_o[ct], 0, 0, 0);
        }
    }

    // ---- epilogue: out[n][c][i] = alpha * O[i][c] / l[i] + x[n][c][i] ----
    const float alpha = alphap[0];
    float rinv[4];
    #pragma unroll
    for (int r = 0; r < 4; ++r) rinv[r] = 1.f / l_[r];

    const float* xB = x   + (size_t)nb * NCH * L_SEQ;
    float*       oB = out + (size_t)nb * NCH * L_SEQ;
    #pragma unroll
    for (int ct = 0; ct < 4; ++ct) {
        const int c = ct * 16 + lo;
        #pragma unroll
        for (int r = 0; r < 4; ++r) {
            const int i = i0 + hi * 4 + r;
            const size_t idx = (size_t)c * L_SEQ + i;
            oB[idx] = alpha * acc_o[ct][r] * rinv[r] + xB[idx];
        }
    }
}

extern "C" void kernel_launch(void* const* d_in, const int* in_sizes, int n_in,
                              void* d_out, int out_size, void* d_ws, size_t ws_size,
                              hipStream_t stream) {
    const float* x     = (const float*)d_in[0];
    const float* wb    = (const float*)d_in[1];
    const float* bb    = (const float*)d_in[2];
    const float* wc    = (const float*)d_in[3];
    const float* bc    = (const float*)d_in[4];
    const float* wd    = (const float*)d_in[5];
    const float* bd    = (const float*)d_in[6];
    const float* alpha = (const float*)d_in[7];

    const size_t elems = (size_t)NBATCH * L_SEQ * NCH;  // 1,048,576
    u16* Qt = (u16*)d_ws;
    u16* Kt = Qt + elems;
    u16* V  = Kt + elems;

    qkv_kernel<<<dim3(L_SEQ / 64, NBATCH), 256, 0, stream>>>(
        x, wb, bb, wc, bc, wd, bd, Qt, Kt, V);
    attn_kernel<<<dim3(L_SEQ / 16, NBATCH), 64, 0, stream>>>(
        Qt, Kt, V, x, alpha, (float*)d_out);
}

// Round 2
// 151.641 us; speedup vs baseline: 1.0832x; 1.0832x over previous
//
#include <hip/hip_runtime.h>
#include <hip/hip_bf16.h>

typedef unsigned short u16;
typedef unsigned int u32;
typedef __attribute__((ext_vector_type(8))) short short8;
typedef __attribute__((ext_vector_type(4))) float f32x4;

#define L_SEQ 4096
#define NCH 64
#define NBATCH 4
#define NW 8                    // waves per block = KV splits
#define KVSPAN (L_SEQ / NW)     // 512 j per wave

__device__ inline u16 f2bf(float f) {
    union { float f; u32 u; } v; v.f = f;
    u32 r = v.u + 0x7fffu + ((v.u >> 16) & 1u);   // round-to-nearest-even
    return (u16)(r >> 16);
}

// ---------------- Kernel 1: QKV projection (3x 64x64 channel GEMM) ----------------
// Qt[n][i][c] (bf16), Kt[n][j][c] (bf16), V[n][c][j] (bf16)
__global__ __launch_bounds__(256) void qkv_kernel(
    const float* __restrict__ x,
    const float* __restrict__ wb, const float* __restrict__ bb,
    const float* __restrict__ wc, const float* __restrict__ bc,
    const float* __restrict__ wd, const float* __restrict__ bd,
    u16* __restrict__ Qt, u16* __restrict__ Kt, u16* __restrict__ V)
{
    __shared__ float xs[64][64];       // x tile: [c][px]
    __shared__ float wl[3][64][65];    // padded weights: [mat][o][c]

    const int nb  = blockIdx.y;
    const int i0  = blockIdx.x * 64;
    const int tid = threadIdx.x;

    const float* xbase = x + (size_t)nb * NCH * L_SEQ + i0;
    #pragma unroll
    for (int rep = 0; rep < 16; ++rep) {
        int idx = rep * 256 + tid;
        int c = idx >> 6, px = idx & 63;
        xs[c][px] = xbase[(size_t)c * L_SEQ + px];
    }
    const float* wsrc[3] = { wb, wc, wd };
    for (int m = 0; m < 3; ++m) {
        #pragma unroll
        for (int rep = 0; rep < 16; ++rep) {
            int idx = rep * 256 + tid;
            wl[m][idx >> 6][idx & 63] = wsrc[m][idx];
        }
    }
    __syncthreads();

    const int co  = tid & 63;     // output channel
    const int pg  = tid >> 6;     // pixel group 0..3
    const int px0 = pg * 16;

    float accB[16], accC[16], accD[16];
    const float biasB = bb[co], biasC = bc[co], biasD = bd[co];
    #pragma unroll
    for (int p = 0; p < 16; ++p) { accB[p] = biasB; accC[p] = biasC; accD[p] = biasD; }

    for (int c = 0; c < 64; ++c) {
        const float wbv = wl[0][co][c];
        const float wcv = wl[1][co][c];
        const float wdv = wl[2][co][c];
        #pragma unroll
        for (int p = 0; p < 16; ++p) {
            const float xv = xs[c][px0 + p];
            accB[p] += wbv * xv;
            accC[p] += wcv * xv;
            accD[p] += wdv * xv;
        }
    }

    #pragma unroll
    for (int p = 0; p < 16; ++p) {
        const int i = i0 + px0 + p;
        Kt[((size_t)(nb * L_SEQ + i)) * NCH + co] = f2bf(accB[p]);  // keys    = xb
        Qt[((size_t)(nb * L_SEQ + i)) * NCH + co] = f2bf(accC[p]);  // queries = xc
        V [((size_t)(nb * NCH + co)) * L_SEQ + i] = f2bf(accD[p]);  // values  = xd
    }
}

// ---------------- Kernel 2: flash attention, split-KV within block ----------------
// Block = 8 waves, one q-tile of 16 rows. Wave w covers j in [w*512, w*512+512).
// Per-wave partial (m, l, O) combined through LDS at the end; epilogue in-block.
__global__ __launch_bounds__(512, 8) void attn_kernel(
    const u16* __restrict__ Qt, const u16* __restrict__ Kt,
    const u16* __restrict__ V,  const float* __restrict__ x,
    const float* __restrict__ alphap, float* __restrict__ out)
{
    // Per-wave region: 16*65 floats (4160 B). During the KV loop the first
    // 2304 B are the wave-private P-transpose buffer (u16[16][72]); after the
    // loop the region is reused for the fp32 partial O[16][65] (padded).
    __shared__ float smem[NW][16 * 65];
    __shared__ float mlbuf[NW][16][2];

    const int nb   = blockIdx.y;
    const int i0   = blockIdx.x * 16;
    const int tid  = threadIdx.x;
    const int w    = tid >> 6;
    const int lane = tid & 63;
    const int lo   = lane & 15;
    const int hi   = lane >> 4;

    u16* pbuf = (u16*)(&smem[w][0]);   // [16][72] u16, stride 144 B

    // Q fragments: A[row=lo][k=c], c contiguous per lane (same q-tile for all waves)
    short8 qf0, qf1;
    {
        const u16* qrow = Qt + ((size_t)(nb * L_SEQ + i0 + lo)) * NCH + hi * 8;
        qf0 = *(const short8*)(qrow);
        qf1 = *(const short8*)(qrow + 32);
    }

    const f32x4 zero = { 0.f, 0.f, 0.f, 0.f };
    f32x4 acc_o[4];
    #pragma unroll
    for (int ct = 0; ct < 4; ++ct) acc_o[ct] = zero;
    float m_[4], l_[4];
    #pragma unroll
    for (int r = 0; r < 4; ++r) { m_[r] = -3.0e38f; l_[r] = 0.f; }

    const u16* KtB = Kt + (size_t)nb * L_SEQ * NCH;
    const u16* VB  = V  + (size_t)nb * NCH * L_SEQ;

    #pragma unroll 1
    for (int t = 0; t < KVSPAN / 64; ++t) {
        const int j0 = w * KVSPAN + t * 64;

        // ---- S = Q K^T (16 x 64) ----
        f32x4 s[4];
        #pragma unroll
        for (int jt = 0; jt < 4; ++jt) {
            const u16* krow = KtB + ((size_t)(j0 + jt * 16 + lo)) * NCH + hi * 8;
            short8 k0 = *(const short8*)(krow);
            short8 k1 = *(const short8*)(krow + 32);
            f32x4 a = zero;
            a = __builtin_amdgcn_mfma_f32_16x16x32_bf16(qf0, k0, a, 0, 0, 0);
            a = __builtin_amdgcn_mfma_f32_16x16x32_bf16(qf1, k1, a, 0, 0, 0);
            s[jt] = a;
        }

        // ---- online softmax; D-layout: row q = hi*4 + r, col j = jt*16 + lo ----
        float scl[4];
        float pv[4][4];  // [jt][r]
        #pragma unroll
        for (int r = 0; r < 4; ++r) {
            float rm = fmaxf(fmaxf(s[0][r], s[1][r]), fmaxf(s[2][r], s[3][r]));
            #pragma unroll
            for (int msk = 1; msk < 16; msk <<= 1)
                rm = fmaxf(rm, __shfl_xor(rm, msk, 64));
            const float mn = fmaxf(m_[r], rm);
            scl[r] = __expf(m_[r] - mn);
            float rs = 0.f;
            #pragma unroll
            for (int jt = 0; jt < 4; ++jt) {
                const float p = __expf(s[jt][r] - mn);
                pv[jt][r] = p;
                rs += p;
            }
            #pragma unroll
            for (int msk = 1; msk < 16; msk <<= 1)
                rs += __shfl_xor(rs, msk, 64);
            l_[r] = l_[r] * scl[r] + rs;
            m_[r] = mn;
        }

        // ---- P -> per-wave LDS (transpose to A-fragment layout) ----
        #pragma unroll
        for (int jt = 0; jt < 4; ++jt)
            #pragma unroll
            for (int r = 0; r < 4; ++r)
                pbuf[(hi * 4 + r) * 72 + jt * 16 + lo] = f2bf(pv[jt][r]);

        // wave-private buffer: only need this wave's LDS ops drained (in-order
        // LDS pipe per wave); no block barrier. sched_barrier per rule 18.
        asm volatile("s_waitcnt lgkmcnt(0)" ::: "memory");
        __builtin_amdgcn_sched_barrier(0);

        short8 pf0 = *(const short8*)&pbuf[lo * 72 + hi * 8];
        short8 pf1 = *(const short8*)&pbuf[lo * 72 + 32 + hi * 8];

        // ---- rescale O ----
        #pragma unroll
        for (int ct = 0; ct < 4; ++ct)
            #pragma unroll
            for (int r = 0; r < 4; ++r)
                acc_o[ct][r] *= scl[r];

        // ---- O += P V^T ;  B[k=j][col=c] from V[c][j] (j contiguous) ----
        #pragma unroll
        for (int ct = 0; ct < 4; ++ct) {
            const u16* vrow = VB + ((size_t)(ct * 16 + lo)) * L_SEQ + j0 + hi * 8;
            short8 v0 = *(const short8*)(vrow);
            short8 v1 = *(const short8*)(vrow + 32);
            acc_o[ct] = __builtin_amdgcn_mfma_f32_16x16x32_bf16(pf0, v0, acc_o[ct], 0, 0, 0);
            acc_o[ct] = __builtin_amdgcn_mfma_f32_16x16x32_bf16(pf1, v1, acc_o[ct], 0, 0, 0);
        }
    }

    // ---- write per-wave partial state to LDS ----
    // acc_o depends on the last pbuf reads (data dependency), so these stores
    // cannot be issued before those reads complete.
    #pragma unroll
    for (int ct = 0; ct < 4; ++ct)
        #pragma unroll
        for (int r = 0; r < 4; ++r)
            smem[w][(hi * 4 + r) * 65 + ct * 16 + lo] = acc_o[ct][r];
    if (lo == 0) {
        #pragma unroll
        for (int r = 0; r < 4; ++r) {
            mlbuf[w][hi * 4 + r][0] = m_[r];
            mlbuf[w][hi * 4 + r][1] = l_[r];
        }
    }
    __syncthreads();

    // ---- combine 8 partials + epilogue ----
    // thread -> (q = tid&15, c0 = (tid>>4)*2): covers 16 q x 64 c
    const int q  = tid & 15;
    const int c0 = (tid >> 4) * 2;

    float gm = -3.0e38f;
    #pragma unroll
    for (int s2 = 0; s2 < NW; ++s2) gm = fmaxf(gm, mlbuf[s2][q][0]);

    float Ls = 0.f, O0 = 0.f, O1 = 0.f;
    #pragma unroll
    for (int s2 = 0; s2 < NW; ++s2) {
        const float cf = __expf(mlbuf[s2][q][0] - gm);
        Ls += mlbuf[s2][q][1] * cf;
        O0 += smem[s2][q * 65 + c0]     * cf;
        O1 += smem[s2][q * 65 + c0 + 1] * cf;
    }
    const float rl    = __builtin_amdgcn_rcpf(Ls);
    const float alpha = alphap[0];

    const size_t base0 = ((size_t)(nb * NCH + c0)) * L_SEQ + i0 + q;
    out[base0]         = alpha * O0 * rl + x[base0];
    out[base0 + L_SEQ] = alpha * O1 * rl + x[base0 + L_SEQ];
}

extern "C" void kernel_launch(void* const* d_in, const int* in_sizes, int n_in,
                              void* d_out, int out_size, void* d_ws, size_t ws_size,
                              hipStream_t stream) {
    const float* x     = (const float*)d_in[0];
    const float* wb    = (const float*)d_in[1];
    const float* bb    = (const float*)d_in[2];
    const float* wc    = (const float*)d_in[3];
    const float* bc    = (const float*)d_in[4];
    const float* wd    = (const float*)d_in[5];
    const float* bd    = (const float*)d_in[6];
    const float* alpha = (const float*)d_in[7];

    const size_t elems = (size_t)NBATCH * L_SEQ * NCH;  // 1,048,576
    u16* Qt = (u16*)d_ws;
    u16* Kt = Qt + elems;
    u16* V  = Kt + elems;

    qkv_kernel<<<dim3(L_SEQ / 64, NBATCH), 256, 0, stream>>>(
        x, wb, bb, wc, bc, wd, bd, Qt, Kt, V);
    attn_kernel<<<dim3(L_SEQ / 16, NBATCH), 512, 0, stream>>>(
        Qt, Kt, V, x, alpha, (float*)d_out);
}

// Round 3
// 134.579 us; speedup vs baseline: 1.2205x; 1.1268x over previous
//
#include <hip/hip_runtime.h>
#include <hip/hip_bf16.h>

typedef unsigned short u16;
typedef unsigned int u32;
typedef __attribute__((ext_vector_type(8))) short short8;
typedef __attribute__((ext_vector_type(4))) float f32x4;

#define L_SEQ 4096
#define NCH 64
#define NBATCH 4
#define NW 8                    // waves per block = KV splits
#define KVSPAN (L_SEQ / NW)     // 512 j per wave

__device__ inline u16 f2bf(float f) {
    union { float f; u32 u; } v; v.f = f;
    u32 r = v.u + 0x7fffu + ((v.u >> 16) & 1u);   // round-to-nearest-even
    return (u16)(r >> 16);
}

// ---------------- Kernel 1: QKV projection (3x 64x64 channel GEMM) ----------------
// Qt[n][i][c] (bf16), Kt[n][j][c] (bf16), V[n][c][j] (bf16)
__global__ __launch_bounds__(256) void qkv_kernel(
    const float* __restrict__ x,
    const float* __restrict__ wb, const float* __restrict__ bb,
    const float* __restrict__ wc, const float* __restrict__ bc,
    const float* __restrict__ wd, const float* __restrict__ bd,
    u16* __restrict__ Qt, u16* __restrict__ Kt, u16* __restrict__ V)
{
    __shared__ float xs[64][64];       // x tile: [c][px]
    __shared__ float wl[3][64][65];    // padded weights: [mat][o][c]

    const int nb  = blockIdx.y;
    const int i0  = blockIdx.x * 64;
    const int tid = threadIdx.x;

    const float* xbase = x + (size_t)nb * NCH * L_SEQ + i0;
    #pragma unroll
    for (int rep = 0; rep < 16; ++rep) {
        int idx = rep * 256 + tid;
        int c = idx >> 6, px = idx & 63;
        xs[c][px] = xbase[(size_t)c * L_SEQ + px];
    }
    const float* wsrc[3] = { wb, wc, wd };
    for (int m = 0; m < 3; ++m) {
        #pragma unroll
        for (int rep = 0; rep < 16; ++rep) {
            int idx = rep * 256 + tid;
            wl[m][idx >> 6][idx & 63] = wsrc[m][idx];
        }
    }
    __syncthreads();

    const int co  = tid & 63;     // output channel
    const int pg  = tid >> 6;     // pixel group 0..3
    const int px0 = pg * 16;

    float accB[16], accC[16], accD[16];
    const float biasB = bb[co], biasC = bc[co], biasD = bd[co];
    #pragma unroll
    for (int p = 0; p < 16; ++p) { accB[p] = biasB; accC[p] = biasC; accD[p] = biasD; }

    for (int c = 0; c < 64; ++c) {
        const float wbv = wl[0][co][c];
        const float wcv = wl[1][co][c];
        const float wdv = wl[2][co][c];
        #pragma unroll
        for (int p = 0; p < 16; ++p) {
            const float xv = xs[c][px0 + p];
            accB[p] += wbv * xv;
            accC[p] += wcv * xv;
            accD[p] += wdv * xv;
        }
    }

    #pragma unroll
    for (int p = 0; p < 16; ++p) {
        const int i = i0 + px0 + p;
        Kt[((size_t)(nb * L_SEQ + i)) * NCH + co] = f2bf(accB[p]);  // keys    = xb
        Qt[((size_t)(nb * L_SEQ + i)) * NCH + co] = f2bf(accC[p]);  // queries = xc
        V [((size_t)(nb * NCH + co)) * L_SEQ + i] = f2bf(accD[p]);  // values  = xd
    }
}

// ---------------- Kernel 2: flash attention, split-KV within block ----------------
// Block = 8 waves, one q-tile of 16 rows. Wave w covers j in [w*512, w*512+512).
// Per-wave partial (m, l, O) combined through LDS at the end; epilogue in-block.
// launch_bounds(512, 4): 128-VGPR budget — R1's (512,8) forced VGPR=32 and
// spilled ~60 regs to scratch (FETCH +14MB, dur flat). 4 waves/SIMD, no spill.
__global__ __launch_bounds__(512, 4) void attn_kernel(
    const u16* __restrict__ Qt, const u16* __restrict__ Kt,
    const u16* __restrict__ V,  const float* __restrict__ x,
    const float* __restrict__ alphap, float* __restrict__ out)
{
    // Per-wave region: 16*65 floats (4160 B). During the KV loop the first
    // 2304 B are the wave-private P-transpose buffer (u16[16][72]); after the
    // loop the region is reused for the fp32 partial O[16][65] (padded).
    __shared__ float smem[NW][16 * 65];
    __shared__ float mlbuf[NW][16][2];

    const int nb   = blockIdx.y;
    const int i0   = blockIdx.x * 16;
    const int tid  = threadIdx.x;
    const int w    = tid >> 6;
    const int lane = tid & 63;
    const int lo   = lane & 15;
    const int hi   = lane >> 4;

    u16* pbuf = (u16*)(&smem[w][0]);   // [16][72] u16, stride 144 B

    // Q fragments: A[row=lo][k=c], c contiguous per lane (same q-tile for all waves)
    short8 qf0, qf1;
    {
        const u16* qrow = Qt + ((size_t)(nb * L_SEQ + i0 + lo)) * NCH + hi * 8;
        qf0 = *(const short8*)(qrow);
        qf1 = *(const short8*)(qrow + 32);
    }

    const f32x4 zero = { 0.f, 0.f, 0.f, 0.f };
    f32x4 acc_o[4];
    #pragma unroll
    for (int ct = 0; ct < 4; ++ct) acc_o[ct] = zero;
    float m_[4], l_[4];
    #pragma unroll
    for (int r = 0; r < 4; ++r) { m_[r] = -3.0e38f; l_[r] = 0.f; }

    const u16* KtB = Kt + (size_t)nb * L_SEQ * NCH;
    const u16* VB  = V  + (size_t)nb * NCH * L_SEQ;

    #pragma unroll 1
    for (int t = 0; t < KVSPAN / 64; ++t) {
        const int j0 = w * KVSPAN + t * 64;

        // ---- S = Q K^T (16 x 64) ----
        f32x4 s[4];
        #pragma unroll
        for (int jt = 0; jt < 4; ++jt) {
            const u16* krow = KtB + ((size_t)(j0 + jt * 16 + lo)) * NCH + hi * 8;
            short8 k0 = *(const short8*)(krow);
            short8 k1 = *(const short8*)(krow + 32);
            f32x4 a = zero;
            a = __builtin_amdgcn_mfma_f32_16x16x32_bf16(qf0, k0, a, 0, 0, 0);
            a = __builtin_amdgcn_mfma_f32_16x16x32_bf16(qf1, k1, a, 0, 0, 0);
            s[jt] = a;
        }

        // ---- online softmax; D-layout: row q = hi*4 + r, col j = jt*16 + lo ----
        float scl[4];
        float pv[4][4];  // [jt][r]
        #pragma unroll
        for (int r = 0; r < 4; ++r) {
            float rm = fmaxf(fmaxf(s[0][r], s[1][r]), fmaxf(s[2][r], s[3][r]));
            #pragma unroll
            for (int msk = 1; msk < 16; msk <<= 1)
                rm = fmaxf(rm, __shfl_xor(rm, msk, 64));
            const float mn = fmaxf(m_[r], rm);
            scl[r] = __expf(m_[r] - mn);
            float rs = 0.f;
            #pragma unroll
            for (int jt = 0; jt < 4; ++jt) {
                const float p = __expf(s[jt][r] - mn);
                pv[jt][r] = p;
                rs += p;
            }
            #pragma unroll
            for (int msk = 1; msk < 16; msk <<= 1)
                rs += __shfl_xor(rs, msk, 64);
            l_[r] = l_[r] * scl[r] + rs;
            m_[r] = mn;
        }

        // ---- P -> per-wave LDS (transpose to A-fragment layout) ----
        #pragma unroll
        for (int jt = 0; jt < 4; ++jt)
            #pragma unroll
            for (int r = 0; r < 4; ++r)
                pbuf[(hi * 4 + r) * 72 + jt * 16 + lo] = f2bf(pv[jt][r]);

        // wave-private buffer: only need this wave's LDS ops drained (in-order
        // LDS pipe per wave); no block barrier. sched_barrier per rule 18.
        asm volatile("s_waitcnt lgkmcnt(0)" ::: "memory");
        __builtin_amdgcn_sched_barrier(0);

        short8 pf0 = *(const short8*)&pbuf[lo * 72 + hi * 8];
        short8 pf1 = *(const short8*)&pbuf[lo * 72 + 32 + hi * 8];

        // ---- rescale O ----
        #pragma unroll
        for (int ct = 0; ct < 4; ++ct)
            #pragma unroll
            for (int r = 0; r < 4; ++r)
                acc_o[ct][r] *= scl[r];

        // ---- O += P V^T ;  B[k=j][col=c] from V[c][j] (j contiguous) ----
        #pragma unroll
        for (int ct = 0; ct < 4; ++ct) {
            const u16* vrow = VB + ((size_t)(ct * 16 + lo)) * L_SEQ + j0 + hi * 8;
            short8 v0 = *(const short8*)(vrow);
            short8 v1 = *(const short8*)(vrow + 32);
            acc_o[ct] = __builtin_amdgcn_mfma_f32_16x16x32_bf16(pf0, v0, acc_o[ct], 0, 0, 0);
            acc_o[ct] = __builtin_amdgcn_mfma_f32_16x16x32_bf16(pf1, v1, acc_o[ct], 0, 0, 0);
        }
    }

    // ---- write per-wave partial state to LDS ----
    // acc_o depends on the last pbuf reads (data dependency), so these stores
    // cannot be issued before those reads complete.
    #pragma unroll
    for (int ct = 0; ct < 4; ++ct)
        #pragma unroll
        for (int r = 0; r < 4; ++r)
            smem[w][(hi * 4 + r) * 65 + ct * 16 + lo] = acc_o[ct][r];
    if (lo == 0) {
        #pragma unroll
        for (int r = 0; r < 4; ++r) {
            mlbuf[w][hi * 4 + r][0] = m_[r];
            mlbuf[w][hi * 4 + r][1] = l_[r];
        }
    }
    __syncthreads();

    // ---- combine 8 partials + epilogue ----
    // thread -> (q = tid&15, c0 = (tid>>4)*2): covers 16 q x 64 c
    const int q  = tid & 15;
    const int c0 = (tid >> 4) * 2;

    float gm = -3.0e38f;
    #pragma unroll
    for (int s2 = 0; s2 < NW; ++s2) gm = fmaxf(gm, mlbuf[s2][q][0]);

    float Ls = 0.f, O0 = 0.f, O1 = 0.f;
    #pragma unroll
    for (int s2 = 0; s2 < NW; ++s2) {
        const float cf = __expf(mlbuf[s2][q][0] - gm);
        Ls += mlbuf[s2][q][1] * cf;
        O0 += smem[s2][q * 65 + c0]     * cf;
        O1 += smem[s2][q * 65 + c0 + 1] * cf;
    }
    const float rl    = __builtin_amdgcn_rcpf(Ls);
    const float alpha = alphap[0];

    const size_t base0 = ((size_t)(nb * NCH + c0)) * L_SEQ + i0 + q;
    out[base0]         = alpha * O0 * rl + x[base0];
    out[base0 + L_SEQ] = alpha * O1 * rl + x[base0 + L_SEQ];
}

extern "C" void kernel_launch(void* const* d_in, const int* in_sizes, int n_in,
                              void* d_out, int out_size, void* d_ws, size_t ws_size,
                              hipStream_t stream) {
    const float* x     = (const float*)d_in[0];
    const float* wb    = (const float*)d_in[1];
    const float* bb    = (const float*)d_in[2];
    const float* wc    = (const float*)d_in[3];
    const float* bc    = (const float*)d_in[4];
    const float* wd    = (const float*)d_in[5];
    const float* bd    = (const float*)d_in[6];
    const float* alpha = (const float*)d_in[7];

    const size_t elems = (size_t)NBATCH * L_SEQ * NCH;  // 1,048,576
    u16* Qt = (u16*)d_ws;
    u16* Kt = Qt + elems;
    u16* V  = Kt + elems;

    qkv_kernel<<<dim3(L_SEQ / 64, NBATCH), 256, 0, stream>>>(
        x, wb, bb, wc, bc, wd, bd, Qt, Kt, V);
    attn_kernel<<<dim3(L_SEQ / 16, NBATCH), 512, 0, stream>>>(
        Qt, Kt, V, x, alpha, (float*)d_out);
}